// Round 6
// baseline (3630.890 us; speedup 1.0000x reference)
//
#include <hip/hip_runtime.h>
#include <hip/hip_cooperative_groups.h>
#include <cstdint>
#include <cstddef>

namespace cg = cooperative_groups;

// Problem constants (reference: B=64, L=512, STEPS=20)
#define LDIM 512
#define BATCH 64
#define NSTEPS 20
#define RPB 128   // rows per block (block owns rows [q*128, q*128+128) of one matrix)
#define QPM 4     // blocks per matrix
#define NTHREADS 1024
#define RPW 8     // rows per wave (16 waves * 8 = 128)
#define CPL 8     // cols per lane (64 lanes * 8 = 512)

__device__ __forceinline__ float relu_f(float x) { return fmaxf(x, 0.0f); }
__device__ __forceinline__ float sign_f(float x) {
  return (x > 0.0f) ? 1.0f : ((x < 0.0f) ? -1.0f : 0.0f);
}
__device__ __forceinline__ float wave_sum(float v) {
  v += __shfl_xor(v, 32);
  v += __shfl_xor(v, 16);
  v += __shfl_xor(v, 8);
  v += __shfl_xor(v, 4);
  v += __shfl_xor(v, 2);
  v += __shfl_xor(v, 1);
  return v;
}
// bf16 pack (RNE) / unpack
__device__ __forceinline__ unsigned short f2bf(float f) {
  unsigned int u = __float_as_uint(f);
  return (unsigned short)((u + 0x7fffu + ((u >> 16) & 1u)) >> 16);
}
__device__ __forceinline__ float bflo(unsigned int d) { return __uint_as_float(d << 16); }
__device__ __forceinline__ float bfhi(unsigned int d) { return __uint_as_float(d & 0xffff0000u); }

// 4-block (per-matrix) barrier. Counter is monotonic (zeroed at kernel start,
// published by the single initial grid.sync). Cooperative launch guarantees
// all 256 blocks are co-resident, so spinning is deadlock-free.
__device__ __forceinline__ void mat_barrier(unsigned int* ctr, unsigned int target) {
  __syncthreads();  // all waves' stores issued before the signal
  if (threadIdx.x == 0) {
    __hip_atomic_fetch_add(ctr, 1u, __ATOMIC_RELEASE, __HIP_MEMORY_SCOPE_AGENT);
    while (__hip_atomic_load(ctr, __ATOMIC_RELAXED, __HIP_MEMORY_SCOPE_AGENT) < target)
      __builtin_amdgcn_s_sleep(1);
  }
  __syncthreads();
  __threadfence();  // acquire: make peers' stores visible before we read them
}

// Persistent cooperative kernel: whole pipeline in ONE launch.
//  - Ah state: 64 fp32 in registers per thread (8 rows x 8 cols).
//    !! no local array's address may escape (no helper taking float*, no
//    reference-capturing lambda touching them): address-taken locals defeat
//    SROA and land in scratch (R2/R5: 2.1 GB scratch traffic).
//    !! all loops indexing a[][] fully unrolled (R4: runtime index -> scratch).
//  - explicit amdgpu_waves_per_eu(4,4): 2048-reg file / 4 waves/EU = 128-VGPR
//    budget (HIP __launch_bounds__ 2nd arg showed no effect R5).
//  - MU = masked symmetrized scores: bf16 in LDS (128 KiB), sentinel -1e30
//  - cross-step coupling: row/col partials via global + 4-block barrier
__global__ __attribute__((amdgpu_flat_work_group_size(NTHREADS, NTHREADS)))
__attribute__((amdgpu_waves_per_eu(4, 4)))
void fused_all(
    const float* __restrict__ scores, const float* __restrict__ Mmask,
    const float* __restrict__ rho_p, const float* __restrict__ s_ptr,
    const float* __restrict__ w_ptr, const float* __restrict__ alpha_ptr,
    const float* __restrict__ belt_ptr, const float* __restrict__ lra_ptr,
    const float* __restrict__ lrb_ptr, float* __restrict__ out,
    float* __restrict__ stage, float* __restrict__ rowsum0,
    float* __restrict__ rowsum1, float* __restrict__ colpart0,
    float* __restrict__ colpart1, unsigned int* __restrict__ ctrs) {
  __shared__ unsigned short MUs[RPB][LDIM];  // 128 KiB
  __shared__ float LmS[LDIM];                // 2 KiB  (per-matrix Lm, replicated)
  __shared__ float lmsgS[LDIM];              // 2 KiB
  __shared__ float colredS[8][LDIM];         // 16 KiB
  __shared__ float rowredS[RPB];             // 0.5 KiB

  cg::grid_group grid = cg::this_grid();

  const int tid = threadIdx.x;
  const int lane = tid & 63;
  const int wid = tid >> 6;
  const int mat = blockIdx.x >> 2;
  const int q = blockIdx.x & 3;
  const int r0 = q * RPB;
  const int j0 = lane * CPL;

  unsigned int* myctr = ctrs + (size_t)mat * 32;  // 128 B apart per matrix
  if (q == 0 && tid == 0) *myctr = 0u;  // published by the initial grid.sync

  const float sval = s_ptr[0];
  const float wv = w_ptr[0];
  const float lra = lra_ptr[0];
  const float lrb = lrb_ptr[0];
  float at = alpha_ptr[0];   // alpha * lra^t, updated per step
  float bm = belt_ptr[0];    // belt * lrb^(t-1) for t>=1, updated per step

  const size_t matbase = (size_t)mat * LDIM * LDIM;

  float a[RPW][CPL];     // register-resident state; constant indices ONLY
  float colacc[CPL];
  float rowacc[RPW];

  // ---------------- init: load scores, build MU, partials of A0 ----------------
#pragma unroll
  for (int r = 0; r < RPW; r++) {
    const float* p = scores + matbase + (size_t)(r0 + wid * RPW + r) * LDIM + j0;
    const float4 v0 = *(const float4*)p;
    const float4 v1 = *(const float4*)(p + 4);
    a[r][0] = v0.x; a[r][1] = v0.y; a[r][2] = v0.z; a[r][3] = v0.w;
    a[r][4] = v1.x; a[r][5] = v1.y; a[r][6] = v1.z; a[r][7] = v1.w;
    rowacc[r] = 0.0f;
  }
#pragma unroll
  for (int c = 0; c < CPL; c++) {
    const int j = j0 + c;
    // column slice via transposed rows; M is symmetric so M[j][i] == M[i][j]
    const float* pt = scores + matbase + (size_t)j * LDIM + r0 + wid * RPW;
    const float* pm = Mmask + matbase + (size_t)j * LDIM + r0 + wid * RPW;
    const float4 t0 = *(const float4*)pt;
    const float4 t1 = *(const float4*)(pt + 4);
    const float4 m0 = *(const float4*)pm;
    const float4 m1 = *(const float4*)(pm + 4);
    const float tT[RPW] = {t0.x, t0.y, t0.z, t0.w, t1.x, t1.y, t1.z, t1.w};
    const float mT[RPW] = {m0.x, m0.y, m0.z, m0.w, m1.x, m1.y, m1.z, m1.w};
    float cacc = 0.0f;
#pragma unroll
    for (int r = 0; r < RPW; r++) {
      const float mu = 0.5f * (a[r][c] + tT[r]) - sval;
      const bool msk = (mT[r] != 0.0f);
      const float contrib = msk ? (mu + sval) : 0.0f;  // = A0 element (symmetric)
      rowacc[r] += contrib;
      cacc += contrib;
      MUs[wid * RPW + r][j] = f2bf(msk ? mu : -1e30f);
    }
    colacc[c] = cacc;
  }
#pragma unroll
  for (int r = 0; r < RPW; r++) {
    const float tot = wave_sum(rowacc[r]);
    if (lane == 0) rowredS[wid * RPW + r] = tot;
  }

  // ---- reduce+publish (inline, macro to avoid ref-capturing lambda) ----
#define REDUCE_PUBLISH(rowsumW, colpartW)                                      \
  do {                                                                         \
    __syncthreads();                                                           \
    if (wid < 8) {                                                             \
      *(float4*)&colredS[wid][j0] =                                            \
          make_float4(colacc[0], colacc[1], colacc[2], colacc[3]);             \
      *(float4*)&colredS[wid][j0 + 4] =                                        \
          make_float4(colacc[4], colacc[5], colacc[6], colacc[7]);             \
    }                                                                          \
    __syncthreads();                                                           \
    if (wid >= 8) {                                                            \
      float4 u0 = *(const float4*)&colredS[wid - 8][j0];                       \
      float4 u1 = *(const float4*)&colredS[wid - 8][j0 + 4];                   \
      u0.x += colacc[0]; u0.y += colacc[1]; u0.z += colacc[2];                 \
      u0.w += colacc[3];                                                       \
      u1.x += colacc[4]; u1.y += colacc[5]; u1.z += colacc[6];                 \
      u1.w += colacc[7];                                                       \
      *(float4*)&colredS[wid - 8][j0] = u0;                                    \
      *(float4*)&colredS[wid - 8][j0 + 4] = u1;                                \
    }                                                                          \
    __syncthreads();                                                           \
    if (tid < LDIM) {                                                          \
      float cs = 0.0f;                                                         \
      _Pragma("unroll") for (int k = 0; k < 8; k++) cs += colredS[k][tid];     \
      (colpartW)[((size_t)mat * QPM + q) * LDIM + tid] = cs;                   \
    } else if (tid < LDIM + RPB) {                                             \
      (rowsumW)[(size_t)mat * LDIM + r0 + (tid - LDIM)] = rowredS[tid - LDIM]; \
    }                                                                          \
  } while (0)

  REDUCE_PUBLISH(rowsum0, colpart0);
  grid.sync();  // covers: init partials + zeroed barrier counters

  // ---------------- 20 fused steps ----------------
#pragma unroll 1
  for (int t = 0; t < NSTEPS; t++) {
    const float* rowsumR = (t & 1) ? rowsum1 : rowsum0;
    const float* colpartR = (t & 1) ? colpart1 : colpart0;
    float* rowsumW = (t & 1) ? rowsum0 : rowsum1;
    float* colpartW = (t & 1) ? colpart0 : colpart1;

    // prologue: Lm update + lmsg for all 512 rows of this matrix (redundant/block)
    if (tid < LDIM) {
      const float srow = rowsumR[(size_t)mat * LDIM + tid];
      float scol = 0.0f;
#pragma unroll
      for (int q2 = 0; q2 < QPM; q2++)
        scol += colpartR[((size_t)mat * QPM + q2) * LDIM + tid];
      const float rd = 0.5f * (srow + scol) - 1.0f;
      const float lm = (t == 0) ? (wv * relu_f(rd)) : (LmS[tid] + bm * relu_f(rd));
      LmS[tid] = lm;
      lmsgS[tid] = lm * sign_f(rd);
    }
    __syncthreads();

    const float4 l0 = *(const float4*)&lmsgS[j0];
    const float4 l1 = *(const float4*)&lmsgS[j0 + 4];
    const float lmj[CPL] = {l0.x, l0.y, l0.z, l0.w, l1.x, l1.y, l1.z, l1.w};
#pragma unroll
    for (int c = 0; c < CPL; c++) colacc[c] = 0.0f;

#pragma unroll
    for (int r = 0; r < RPW; r++) {
      const int il = wid * RPW + r;
      const int i = r0 + il;
      const float lmi = lmsgS[i];
      const float* rrow = rho_p + (size_t)i * LDIM + j0;
      const uint2 mua = *(const uint2*)&MUs[il][j0];
      const uint2 mub = *(const uint2*)&MUs[il][j0 + 4];
      const float4 rho0 = *(const float4*)rrow;
      const float4 rho1 = *(const float4*)(rrow + 4);
      const float muf[CPL] = {bflo(mua.x), bfhi(mua.x), bflo(mua.y), bfhi(mua.y),
                              bflo(mub.x), bfhi(mub.x), bflo(mub.y), bfhi(mub.y)};
      const float rh[CPL] = {rho0.x, rho0.y, rho0.z, rho0.w,
                             rho1.x, rho1.y, rho1.z, rho1.w};
      float rowc = 0.0f;
#pragma unroll
      for (int c = 0; c < CPL; c++) {
        const bool msk = (muf[c] > -1e29f);
        const float g = msk ? (muf[c] - lmi - lmj[c]) : 0.0f;
        const float u = a[r][c] * fmaf(at, g, 1.0f);
        const float v = fminf(relu_f(fabsf(u) - rh[c] * at), 1.0f);
        a[r][c] = v;
        const float cm = msk ? v : 0.0f;
        rowc += cm;
        colacc[c] += cm;
      }
      const float tot = wave_sum(rowc);
      if (lane == 0) rowredS[il] = tot;
    }

    REDUCE_PUBLISH(rowsumW, colpartW);
    mat_barrier(myctr, 4u * (unsigned)(t + 1));

    at *= lra;
    if (t >= 1) bm *= lrb;
  }

  // ---------------- final: A = 0.5*(Ah + Ah^T) .* M ----------------
#pragma unroll
  for (int r = 0; r < RPW; r++) {
    float* p = stage + matbase + (size_t)(r0 + wid * RPW + r) * LDIM + j0;
    *(float4*)p = make_float4(a[r][0], a[r][1], a[r][2], a[r][3]);
    *(float4*)(p + 4) = make_float4(a[r][4], a[r][5], a[r][6], a[r][7]);
  }
  mat_barrier(myctr, 4u * (unsigned)(NSTEPS + 1));

#pragma unroll
  for (int c = 0; c < CPL; c++) {
    const int j = j0 + c;
    const float* pt = stage + matbase + (size_t)j * LDIM + r0 + wid * RPW;
    const float4 t0 = *(const float4*)pt;
    const float4 t1 = *(const float4*)(pt + 4);
    const float tT[RPW] = {t0.x, t0.y, t0.z, t0.w, t1.x, t1.y, t1.z, t1.w};
#pragma unroll
    for (int r = 0; r < RPW; r++) a[r][c] = 0.5f * (a[r][c] + tT[r]);
  }
#pragma unroll
  for (int r = 0; r < RPW; r++) {
    const float* pm = Mmask + matbase + (size_t)(r0 + wid * RPW + r) * LDIM + j0;
    const float4 m0 = *(const float4*)pm;
    const float4 m1 = *(const float4*)(pm + 4);
    float* p = out + matbase + (size_t)(r0 + wid * RPW + r) * LDIM + j0;
    *(float4*)p = make_float4(a[r][0] * m0.x, a[r][1] * m0.y,
                              a[r][2] * m0.z, a[r][3] * m0.w);
    *(float4*)(p + 4) = make_float4(a[r][4] * m1.x, a[r][5] * m1.y,
                                    a[r][6] * m1.z, a[r][7] * m1.w);
  }
}

// ---------------------------------------------------------------------------
extern "C" void kernel_launch(void* const* d_in, const int* in_sizes, int n_in,
                              void* d_out, int out_size, void* d_ws,
                              size_t ws_size, hipStream_t stream) {
  const float* scores = (const float*)d_in[0];
  const float* M = (const float*)d_in[1];
  const float* s_p = (const float*)d_in[2];
  const float* w_p = (const float*)d_in[3];
  const float* rho = (const float*)d_in[4];
  const float* alpha_p = (const float*)d_in[5];
  const float* belt_p = (const float*)d_in[6];
  const float* lra_p = (const float*)d_in[7];
  const float* lrb_p = (const float*)d_in[8];
  float* out = (float*)d_out;

  // workspace: stage (64 MB) + partial double-buffers (~1.3 MB) + barrier ctrs
  char* ws = (char*)d_ws;
  size_t off = 0;
  auto walloc = [&](size_t bytes) -> void* {
    void* p = (void*)(ws + off);
    off += (bytes + 255) & ~(size_t)255;
    return p;
  };
  float* stage = (float*)walloc((size_t)BATCH * LDIM * LDIM * 4);
  float* rowsum0 = (float*)walloc((size_t)BATCH * LDIM * 4);
  float* rowsum1 = (float*)walloc((size_t)BATCH * LDIM * 4);
  float* colpart0 = (float*)walloc((size_t)BATCH * QPM * LDIM * 4);
  float* colpart1 = (float*)walloc((size_t)BATCH * QPM * LDIM * 4);
  unsigned int* ctrs = (unsigned int*)walloc((size_t)BATCH * 32 * 4);

  void* args[] = {
      (void*)&scores,  (void*)&M,        (void*)&rho,     (void*)&s_p,
      (void*)&w_p,     (void*)&alpha_p,  (void*)&belt_p,  (void*)&lra_p,
      (void*)&lrb_p,   (void*)&out,      (void*)&stage,   (void*)&rowsum0,
      (void*)&rowsum1, (void*)&colpart0, (void*)&colpart1, (void*)&ctrs};

  (void)hipLaunchCooperativeKernel((void*)fused_all, dim3(BATCH * QPM),
                                   dim3(NTHREADS), args, 0, stream);
}